// Round 3
// baseline (297.032 us; speedup 1.0000x reference)
//
#include <hip/hip_runtime.h>
#include <hip/hip_cooperative_groups.h>

namespace cg = cooperative_groups;

#define I_FEAT 8192
#define O_FEAT 8192
#define BATCH  1024

// Phase A geometry: 128 row-splits x 8 col-blocks = 1024 blocks
#define NS   128
#define RPS  (O_FEAT / NS)   // 64 rows per split

using f4 = __attribute__((ext_vector_type(4))) float;

// Single fused cooperative kernel.
// 1024 blocks x 256 threads; __launch_bounds__(256,4) -> 4 waves/EU
// = 4 blocks/CU = 1024 blocks co-resident on 256 CUs.
__global__ __launch_bounds__(256, 4) void fused_linear_sum_kernel(
    const float* __restrict__ x, const float* __restrict__ W,
    const float* __restrict__ b, float* __restrict__ out,
    float* __restrict__ partials, float* __restrict__ colsum,
    float* __restrict__ bsum) {
  cg::grid_group grid = cg::this_grid();
  __shared__ float red[4];
  const int bid = blockIdx.x;
  const int t   = threadIdx.x;

  // ---------- Phase A: partial column sums of W (reads 256 MB) ----------
  {
    const int cb    = bid & 7;
    const int split = bid >> 3;
    const int c     = (cb << 10) | (t << 2);
    const float* base = W + (size_t)split * RPS * I_FEAT + c;

    f4 acc[8];
#pragma unroll
    for (int u = 0; u < 8; ++u) acc[u] = (f4)(0.f);

    for (int r = 0; r < RPS; r += 8) {
#pragma unroll
      for (int u = 0; u < 8; ++u)
        acc[u] += *(const f4*)(base + (size_t)(r + u) * I_FEAT);
    }
    f4 s = ((acc[0] + acc[1]) + (acc[2] + acc[3])) +
           ((acc[4] + acc[5]) + (acc[6] + acc[7]));
    *(f4*)(partials + (size_t)split * I_FEAT + c) = s;
  }

  grid.sync();

  // ---------- Phase B: partials -> colsum (blocks 0..7); b -> bsum (block 8) ----
  if (bid < 8) {
    const int c = (bid << 10) | (t << 2);
    f4 s = (f4)(0.f);
#pragma unroll 8
    for (int sp = 0; sp < NS; ++sp)
      s += *(const f4*)(partials + (size_t)sp * I_FEAT + c);
    *(f4*)(colsum + c) = s;
  } else if (bid == 8) {
    float s = 0.f;
    const f4* b4 = (const f4*)b;
    for (int j = t; j < O_FEAT / 4; j += 256) {
      f4 v = b4[j];
      s += (v.x + v.y) + (v.z + v.w);
    }
#pragma unroll
    for (int off = 32; off; off >>= 1) s += __shfl_down(s, off);
    if ((t & 63) == 0) red[t >> 6] = s;
    __syncthreads();
    if (t == 0) bsum[0] = (red[0] + red[1]) + (red[2] + red[3]);
  }

  grid.sync();

  // ---------- Phase C: out[row] = dot(x[row], colsum) + bsum (reads 32 MB) ----
  {
    const int row = bid;  // 1024 blocks == 1024 rows
    const f4* xr = (const f4*)(x + (size_t)row * I_FEAT);
    const f4* cs = (const f4*)colsum;

    float s = 0.f;
#pragma unroll
    for (int j = 0; j < 8; ++j) {  // 8 * 256 * 4 = 8192
      const int idx = t + j * 256;
      f4 a = xr[idx];
      f4 c = cs[idx];
      s += a.x * c.x + a.y * c.y + a.z * c.z + a.w * c.w;
    }
#pragma unroll
    for (int off = 32; off; off >>= 1) s += __shfl_down(s, off);
    if ((t & 63) == 0) red[t >> 6] = s;
    __syncthreads();
    if (t == 0)
      out[row] = (red[0] + red[1]) + (red[2] + red[3]) + bsum[0];
  }
}

extern "C" void kernel_launch(void* const* d_in, const int* in_sizes, int n_in,
                              void* d_out, int out_size, void* d_ws, size_t ws_size,
                              hipStream_t stream) {
  const float* x = (const float*)d_in[0];  // (1024, 8192)
  const float* W = (const float*)d_in[1];  // (8192, 8192)
  const float* b = (const float*)d_in[2];  // (8192,)
  float* out = (float*)d_out;              // (1024,)

  // ws layout: partials [128][8192] f32 (4 MB) | colsum [8192] f32 | bsum f32
  float* partials = (float*)d_ws;
  float* colsum   = partials + (size_t)NS * I_FEAT;
  float* bsum     = colsum + I_FEAT;

  void* args[] = {(void*)&x, (void*)&W, (void*)&b, (void*)&out,
                  (void*)&partials, (void*)&colsum, (void*)&bsum};
  hipLaunchCooperativeKernel((void*)fused_linear_sum_kernel,
                             dim3(NS * 8), dim3(256), args, 0, stream);
}

// Round 4
// 61.937 us; speedup vs baseline: 4.7957x; 4.7957x over previous
//
#include <hip/hip_runtime.h>

#define I_FEAT 8192
#define O_FEAT 8192
#define BATCH  1024

// K1 geometry: blocks own contiguous 2048-col x 32-row panels of W.
#define NS        256                 // row-splits (8192/32)
#define ROWS_PB   32
#define CCHUNKS   4                   // 8192 cols / 2048
#define SGROUPS   8                   // K2a reduces 256 splits -> 8 groups

using f4 = __attribute__((ext_vector_type(4))) float;

// ---------------- K1: partial column sums over contiguous panels ----------
__global__ __launch_bounds__(256) void colsum_partial_kernel(
    const float* __restrict__ W, float* __restrict__ partials) {
  const int chunk = blockIdx.x & (CCHUNKS - 1);
  const int split = blockIdx.x / CCHUNKS;
  const int t = threadIdx.x;
  const int c = (chunk << 11) + (t << 2);  // chunk*2048 + t*4

  const float* base = W + (size_t)split * ROWS_PB * I_FEAT + c;

  // 4 rotating accumulator slots x 2 column-groups; unroll 8 -> 16 loads in flight
  f4 acc[4][2];
#pragma unroll
  for (int s = 0; s < 4; ++s) { acc[s][0] = (f4)(0.f); acc[s][1] = (f4)(0.f); }

#pragma unroll 8
  for (int r = 0; r < ROWS_PB; ++r) {
    const float* rp = base + (size_t)r * I_FEAT;
    acc[r & 3][0] += *(const f4*)(rp);
    acc[r & 3][1] += *(const f4*)(rp + 1024);
  }

  f4 s0 = (acc[0][0] + acc[1][0]) + (acc[2][0] + acc[3][0]);
  f4 s1 = (acc[0][1] + acc[1][1]) + (acc[2][1] + acc[3][1]);
  float* o = partials + (size_t)split * I_FEAT + c;
  *(f4*)o = s0;
  *(f4*)(o + 1024) = s1;
}

// ------- K2a: partials[256] -> p2[8] per 1024-col slice; block 64: bsum ----
__global__ __launch_bounds__(256) void reduce1_kernel(
    const float* __restrict__ partials, const float* __restrict__ b,
    float* __restrict__ p2, float* __restrict__ bsum) {
  __shared__ float red[4];
  const int t = threadIdx.x;
  if (blockIdx.x < 64) {
    const int cb = blockIdx.x & 7;
    const int sg = blockIdx.x >> 3;
    const int c  = (cb << 10) + (t << 2);
    const float* base = partials + (size_t)sg * (NS / SGROUPS) * I_FEAT + c;
    f4 s = (f4)(0.f);
#pragma unroll 8
    for (int sp = 0; sp < NS / SGROUPS; ++sp)  // 32 rows
      s += *(const f4*)(base + (size_t)sp * I_FEAT);
    *(f4*)(p2 + (size_t)sg * I_FEAT + c) = s;
  } else {
    float s = 0.f;
    const f4* b4 = (const f4*)b;
    for (int j = t; j < O_FEAT / 4; j += 256) {
      f4 v = b4[j];
      s += (v.x + v.y) + (v.z + v.w);
    }
#pragma unroll
    for (int off = 32; off; off >>= 1) s += __shfl_down(s, off);
    if ((t & 63) == 0) red[t >> 6] = s;
    __syncthreads();
    if (t == 0) bsum[0] = (red[0] + red[1]) + (red[2] + red[3]);
  }
}

// ---------------- K2b: p2[8] -> colsum ----------------
__global__ __launch_bounds__(256) void reduce2_kernel(
    const float* __restrict__ p2, float* __restrict__ colsum) {
  const int c = (blockIdx.x << 10) + (threadIdx.x << 2);
  f4 s = (f4)(0.f);
#pragma unroll
  for (int g = 0; g < SGROUPS; ++g)
    s += *(const f4*)(p2 + (size_t)g * I_FEAT + c);
  *(f4*)(colsum + c) = s;
}

// ---------------- K3: out[row] = dot(x[row], colsum) + bsum ----------------
__global__ __launch_bounds__(256) void rowdot_kernel(
    const float* __restrict__ x, const float* __restrict__ colsum,
    const float* __restrict__ bsum, float* __restrict__ out) {
  __shared__ float red[4];
  const int row = blockIdx.x;
  const int t = threadIdx.x;
  const f4* xr = (const f4*)(x + (size_t)row * I_FEAT);
  const f4* cs = (const f4*)colsum;

  float s = 0.f;
#pragma unroll
  for (int j = 0; j < 8; ++j) {
    const int idx = t + j * 256;
    f4 a = xr[idx];
    f4 c = cs[idx];
    s += a.x * c.x + a.y * c.y + a.z * c.z + a.w * c.w;
  }
#pragma unroll
  for (int off = 32; off; off >>= 1) s += __shfl_down(s, off);
  if ((t & 63) == 0) red[t >> 6] = s;
  __syncthreads();
  if (t == 0)
    out[row] = (red[0] + red[1]) + (red[2] + red[3]) + bsum[0];
}

extern "C" void kernel_launch(void* const* d_in, const int* in_sizes, int n_in,
                              void* d_out, int out_size, void* d_ws, size_t ws_size,
                              hipStream_t stream) {
  const float* x = (const float*)d_in[0];  // (1024, 8192)
  const float* W = (const float*)d_in[1];  // (8192, 8192)
  const float* b = (const float*)d_in[2];  // (8192,)
  float* out = (float*)d_out;              // (1024,)

  // ws: partials [256][8192] f32 (8MB) | p2 [8][8192] (256KB) | colsum | bsum
  float* partials = (float*)d_ws;
  float* p2       = partials + (size_t)NS * I_FEAT;
  float* colsum   = p2 + (size_t)SGROUPS * I_FEAT;
  float* bsum     = colsum + I_FEAT;

  colsum_partial_kernel<<<NS * CCHUNKS, 256, 0, stream>>>(W, partials);
  reduce1_kernel<<<65, 256, 0, stream>>>(partials, b, p2, bsum);
  reduce2_kernel<<<8, 256, 0, stream>>>(p2, colsum);
  rowdot_kernel<<<BATCH, 256, 0, stream>>>(x, colsum, bsum, out);
}